// Round 2
// baseline (186.789 us; speedup 1.0000x reference)
//
#include <hip/hip_runtime.h>
#include <math.h>

#define B_ 2
#define C_ 256
#define H_ 64
#define W_ 64
#define L_ (H_*W_)      // 4096
#define HEADS_ 8
#define DH_ 32          // head dim
#define K_ 7
#define PAD_ 3
#define K2_ 49
#define PW_ 70                        // padded spatial extent (64 + 2*3)
#define PPIX_ (PW_*PW_)               // 4900
#define PADT_ ((size_t)B_*HEADS_*PPIX_*DH_)  // padded K/V tensor elems

// ---------------- Kernel 1: fused QKV projection, NCHW in -> (Q: NHWC, K/V: padded) ---
// q out: qt[(b*L + l)*C + o]
// k/v out: padded [b][head][y+3][x+3][co]  (halo pre-zeroed by memset)
__global__ __launch_bounds__(256) void qkv_proj(
    const float* __restrict__ q_in, const float* __restrict__ k_in, const float* __restrict__ v_in,
    const float* __restrict__ wq, const float* __restrict__ bq,
    const float* __restrict__ wk, const float* __restrict__ bk,
    const float* __restrict__ wv, const float* __restrict__ bv,
    float* __restrict__ qt, float* __restrict__ kt, float* __restrict__ vt)
{
    const int which = blockIdx.z % 3;
    const int b = blockIdx.z / 3;
    const float* in   = (which==0) ? q_in : (which==1 ? k_in : v_in);
    const float* w    = (which==0) ? wq   : (which==1 ? wk   : wv);
    const float* bias = (which==0) ? bq   : (which==1 ? bk   : bv);

    const int l0 = blockIdx.x * 64;   // one full image row (l0 is 64-aligned)
    const int o0 = blockIdx.y * 64;
    const int tx = threadIdx.x, ty = threadIdx.y;
    const int tid = ty*16 + tx;

    __shared__ float As[16][68]; // [c][l]
    __shared__ float Bs[16][68]; // [c][o]

    float acc[4][4] = {}; // [li][oi]

    for (int c0 = 0; c0 < C_; c0 += 16) {
        #pragma unroll
        for (int i = 0; i < 4; ++i) {
            int idx = tid + i*256;
            int c = idx >> 6, l = idx & 63;
            As[c][l] = in[(size_t)(b*C_ + c0 + c)*L_ + l0 + l];
        }
        #pragma unroll
        for (int i = 0; i < 4; ++i) {
            int idx = tid + i*256;
            int o = idx >> 4, c = idx & 15;
            Bs[c][o] = w[(size_t)(o0 + o)*C_ + c0 + c];
        }
        __syncthreads();
        #pragma unroll
        for (int cc = 0; cc < 16; ++cc) {
            float a[4], bb[4];
            #pragma unroll
            for (int i=0;i<4;++i) a[i]  = As[cc][ty*4+i];
            #pragma unroll
            for (int i=0;i<4;++i) bb[i] = Bs[cc][tx*4+i];
            #pragma unroll
            for (int li=0;li<4;++li)
                #pragma unroll
                for (int oi=0;oi<4;++oi)
                    acc[li][oi] += a[li]*bb[oi];
        }
        __syncthreads();
    }

    const int o = o0 + tx*4;
    float4 bias4;
    bias4.x = bias[o+0]; bias4.y = bias[o+1]; bias4.z = bias[o+2]; bias4.w = bias[o+3];

    if (which == 0) {
        #pragma unroll
        for (int li=0;li<4;++li) {
            int l = l0 + ty*4 + li;
            float4 r;
            r.x = acc[li][0] + bias4.x;
            r.y = acc[li][1] + bias4.y;
            r.z = acc[li][2] + bias4.z;
            r.w = acc[li][3] + bias4.w;
            *reinterpret_cast<float4*>(&qt[(size_t)(b*L_ + l)*C_ + o]) = r;
        }
    } else {
        float* outp = (which==1) ? kt : vt;
        const int head = o >> 5;
        const int co   = o & 31;
        const int yq   = l0 >> 6;           // image row for this block
        #pragma unroll
        for (int li=0;li<4;++li) {
            int xq = ty*4 + li;
            float4 r;
            r.x = acc[li][0] + bias4.x;
            r.y = acc[li][1] + bias4.y;
            r.z = acc[li][2] + bias4.z;
            r.w = acc[li][3] + bias4.w;
            size_t off = ((size_t)((b*HEADS_ + head)*PW_ + (yq+PAD_))*PW_ + (xq+PAD_))*DH_ + co;
            *reinterpret_cast<float4*>(&outp[off]) = r;
        }
    }
}

// ---------------- Kernel 2: 7x7 local attention, branch-free via padded K/V ------
// One wave per (b, h, row y); lane = x. Output written in-place over q.
__global__ __launch_bounds__(256, 1) void local_attn(
    float* __restrict__ qt, const float* __restrict__ kt, const float* __restrict__ vt)
{
    const int wave = threadIdx.x >> 6;
    const int lane = threadIdx.x & 63;
    const int y = blockIdx.x*4 + wave;
    const int h = blockIdx.y;
    const int b = blockIdx.z;
    const int x = lane;

    float* qp = qt + ((size_t)(b*L_ + y*W_ + x)*C_ + h*DH_);

    float4 qv[8];
    #pragma unroll
    for (int i=0;i<8;++i) qv[i] = reinterpret_cast<const float4*>(qp)[i];
    const float scale = 0.0625f; // 1/sqrt(256), folded into q
    #pragma unroll
    for (int i=0;i<8;++i) { qv[i].x*=scale; qv[i].y*=scale; qv[i].z*=scale; qv[i].w*=scale; }

    const float* kbase = kt + (size_t)(b*HEADS_ + h)*PPIX_*DH_;
    const float* vbase = vt + (size_t)(b*HEADS_ + h)*PPIX_*DH_;

    // ---- QK: 49 branch-free taps (padded zeros give logit 0, as reference) ----
    float logits[K2_];
    #pragma unroll
    for (int ky=0; ky<K_; ++ky) {
        const float4* krow = reinterpret_cast<const float4*>(kbase + ((size_t)(y+ky)*PW_ + x)*DH_);
        #pragma unroll
        for (int kx=0; kx<K_; ++kx) {
            const float4* kp = krow + kx*8;
            float d = 0.f;
            #pragma unroll
            for (int i=0;i<8;++i) {
                float4 kv = kp[i];
                d += qv[i].x*kv.x + qv[i].y*kv.y + qv[i].z*kv.z + qv[i].w*kv.w;
            }
            logits[ky*K_+kx] = d;
        }
    }

    // ---- softmax over all 49 (OOB logits are exactly 0, in the denominator) ----
    float m = logits[0];
    #pragma unroll
    for (int s=1;s<K2_;++s) m = fmaxf(m, logits[s]);
    float sum = 0.f;
    #pragma unroll
    for (int s=0;s<K2_;++s) { logits[s] = __expf(logits[s]-m); sum += logits[s]; }
    const float inv = 1.0f/sum;

    // ---- PV: 49 branch-free taps, normalize once at the end ----
    float4 acc[8] = {};
    #pragma unroll
    for (int ky=0; ky<K_; ++ky) {
        const float4* vrow = reinterpret_cast<const float4*>(vbase + ((size_t)(y+ky)*PW_ + x)*DH_);
        #pragma unroll
        for (int kx=0; kx<K_; ++kx) {
            float p = logits[ky*K_+kx];
            const float4* vp = vrow + kx*8;
            #pragma unroll
            for (int i=0;i<8;++i) {
                float4 vv = vp[i];
                acc[i].x += p*vv.x; acc[i].y += p*vv.y; acc[i].z += p*vv.z; acc[i].w += p*vv.w;
            }
        }
    }
    float4* op = reinterpret_cast<float4*>(qp);
    #pragma unroll
    for (int i=0;i<8;++i) {
        acc[i].x *= inv; acc[i].y *= inv; acc[i].z *= inv; acc[i].w *= inv;
        op[i] = acc[i];
    }
}

// ---------------- Kernel 3: output projection, NHWC -> NCHW ----------------
__global__ __launch_bounds__(256) void out_proj(
    const float* __restrict__ at, const float* __restrict__ wo, const float* __restrict__ bo,
    float* __restrict__ out)
{
    const int b = blockIdx.z;
    const int l0 = blockIdx.x*64;
    const int o0 = blockIdx.y*64;
    const int tx = threadIdx.x, ty = threadIdx.y;
    const int tid = ty*16+tx;

    __shared__ float As[16][68]; // [c][l]
    __shared__ float Bs[16][68]; // [c][o]

    float acc[4][4] = {}; // [oi][li]

    for (int c0=0;c0<C_;c0+=16) {
        #pragma unroll
        for (int i=0;i<4;++i) {
            int idx = tid + i*256;
            int l = idx >> 4, c = idx & 15;
            As[c][l] = at[(size_t)(b*L_ + l0 + l)*C_ + c0 + c];
        }
        #pragma unroll
        for (int i=0;i<4;++i) {
            int idx = tid + i*256;
            int o = idx >> 4, c = idx & 15;
            Bs[c][o] = wo[(size_t)(o0 + o)*C_ + c0 + c];
        }
        __syncthreads();
        #pragma unroll
        for (int cc=0;cc<16;++cc) {
            float a[4], bb[4];
            #pragma unroll
            for (int i=0;i<4;++i) a[i]  = As[cc][tx*4+i];
            #pragma unroll
            for (int i=0;i<4;++i) bb[i] = Bs[cc][ty*4+i];
            #pragma unroll
            for (int oi=0;oi<4;++oi)
                #pragma unroll
                for (int li=0;li<4;++li)
                    acc[oi][li] += bb[oi]*a[li];
        }
        __syncthreads();
    }
    #pragma unroll
    for (int oi=0;oi<4;++oi) {
        int o = o0 + ty*4 + oi;
        float bias = bo[o];
        float4 r;
        r.x = acc[oi][0] + bias;
        r.y = acc[oi][1] + bias;
        r.z = acc[oi][2] + bias;
        r.w = acc[oi][3] + bias;
        *reinterpret_cast<float4*>(&out[((size_t)b*C_ + o)*L_ + l0 + tx*4]) = r;
    }
}

extern "C" void kernel_launch(void* const* d_in, const int* in_sizes, int n_in,
                              void* d_out, int out_size, void* d_ws, size_t ws_size,
                              hipStream_t stream) {
    const float* queries = (const float*)d_in[0];
    const float* keys    = (const float*)d_in[1];
    const float* values  = (const float*)d_in[2];
    const float* wq = (const float*)d_in[3];
    const float* bq = (const float*)d_in[4];
    const float* wk = (const float*)d_in[5];
    const float* bk = (const float*)d_in[6];
    const float* wv = (const float*)d_in[7];
    const float* bv = (const float*)d_in[8];
    const float* wo = (const float*)d_in[9];
    const float* bo = (const float*)d_in[10];
    float* out = (float*)d_out;

    const size_t q_elems = (size_t)B_ * L_ * C_;   // 2,097,152
    float* qt = (float*)d_ws;                       // Q, then attention output in-place
    float* kt = qt + q_elems;                       // padded K
    float* vt = kt + PADT_;                         // padded V

    // zero the padded halos (interior is overwritten by qkv_proj)
    hipMemsetAsync(kt, 0, PADT_*sizeof(float), stream);
    hipMemsetAsync(vt, 0, PADT_*sizeof(float), stream);

    dim3 blk(16,16);
    qkv_proj<<<dim3(L_/64, C_/64, B_*3), blk, 0, stream>>>(
        queries, keys, values, wq, bq, wk, bk, wv, bv, qt, kt, vt);
    local_attn<<<dim3(H_/4, HEADS_, B_), 256, 0, stream>>>(qt, kt, vt);
    out_proj<<<dim3(L_/64, C_/64, B_), blk, 0, stream>>>(qt, wo, bo, out);
}

// Round 3
// 128.756 us; speedup vs baseline: 1.4507x; 1.4507x over previous
//
#include <hip/hip_runtime.h>
#include <math.h>

#define B_ 2
#define C_ 256
#define H_ 64
#define W_ 64
#define L_ (H_*W_)      // 4096
#define HEADS_ 8
#define DH_ 32          // head dim
#define CG_ 8           // channel groups of 4 floats (float4)
#define K_ 7
#define PAD_ 3
#define K2_ 49
#define PW_ 70                         // padded spatial extent
#define PPIX_ (PW_*PW_)                // 4900
#define PLANES_ (B_*HEADS_*CG_)        // 128 float4 planes per tensor
#define PADT4_ ((size_t)PLANES_*PPIX_) // float4 elems per padded K/V tensor

// ---------------- Kernel 0: zero the padded halo of K/V ----------------
__global__ __launch_bounds__(256) void halo_zero(float4* __restrict__ kt, float4* __restrict__ vt)
{
    int idx = blockIdx.x*256 + threadIdx.x;
    if (idx >= (int)PADT4_) return;
    int cell = idx % PPIX_;
    int px = cell % PW_, py = cell / PW_;
    if (px < PAD_ || px >= PW_-PAD_ || py < PAD_ || py >= PW_-PAD_) {
        float4 z = make_float4(0.f,0.f,0.f,0.f);
        kt[idx] = z;
        vt[idx] = z;
    }
}

// ---------------- Kernel 1: fused QKV projection ----------------
// Q out: NHWC qt[(b*L + l)*C + o]
// K/V out: padded planar-c4 [b][h][cg][y+3][x+3] (float4), halo pre-zeroed
__global__ __launch_bounds__(256) void qkv_proj(
    const float* __restrict__ q_in, const float* __restrict__ k_in, const float* __restrict__ v_in,
    const float* __restrict__ wq, const float* __restrict__ bq,
    const float* __restrict__ wk, const float* __restrict__ bk,
    const float* __restrict__ wv, const float* __restrict__ bv,
    float* __restrict__ qt, float4* __restrict__ kt, float4* __restrict__ vt)
{
    const int which = blockIdx.z % 3;
    const int b = blockIdx.z / 3;
    const float* in   = (which==0) ? q_in : (which==1 ? k_in : v_in);
    const float* w    = (which==0) ? wq   : (which==1 ? wk   : wv);
    const float* bias = (which==0) ? bq   : (which==1 ? bk   : bv);

    const int l0 = blockIdx.x * 64;   // one full image row
    const int o0 = blockIdx.y * 64;
    const int tx = threadIdx.x, ty = threadIdx.y;
    const int tid = ty*16 + tx;

    __shared__ float As[16][68]; // [c][l]
    __shared__ float Bs[16][68]; // [c][o]

    float acc[4][4] = {}; // [li][oi]

    for (int c0 = 0; c0 < C_; c0 += 16) {
        #pragma unroll
        for (int i = 0; i < 4; ++i) {
            int idx = tid + i*256;
            int c = idx >> 6, l = idx & 63;
            As[c][l] = in[(size_t)(b*C_ + c0 + c)*L_ + l0 + l];
        }
        #pragma unroll
        for (int i = 0; i < 4; ++i) {
            int idx = tid + i*256;
            int o = idx >> 4, c = idx & 15;
            Bs[c][o] = w[(size_t)(o0 + o)*C_ + c0 + c];
        }
        __syncthreads();
        #pragma unroll
        for (int cc = 0; cc < 16; ++cc) {
            float a[4], bb[4];
            #pragma unroll
            for (int i=0;i<4;++i) a[i]  = As[cc][ty*4+i];
            #pragma unroll
            for (int i=0;i<4;++i) bb[i] = Bs[cc][tx*4+i];
            #pragma unroll
            for (int li=0;li<4;++li)
                #pragma unroll
                for (int oi=0;oi<4;++oi)
                    acc[li][oi] += a[li]*bb[oi];
        }
        __syncthreads();
    }

    const int o = o0 + tx*4;
    float4 bias4;
    bias4.x = bias[o+0]; bias4.y = bias[o+1]; bias4.z = bias[o+2]; bias4.w = bias[o+3];

    if (which == 0) {
        #pragma unroll
        for (int li=0;li<4;++li) {
            int l = l0 + ty*4 + li;
            float4 r;
            r.x = acc[li][0] + bias4.x;
            r.y = acc[li][1] + bias4.y;
            r.z = acc[li][2] + bias4.z;
            r.w = acc[li][3] + bias4.w;
            *reinterpret_cast<float4*>(&qt[(size_t)(b*L_ + l)*C_ + o]) = r;
        }
    } else {
        float4* outp = (which==1) ? kt : vt;
        const int head = o >> 5;
        const int cg   = (o & 31) >> 2;      // o is a multiple of 4
        const int yq   = l0 >> 6;            // image row of this block
        const size_t plane = ((size_t)(b*HEADS_ + head)*CG_ + cg)*PPIX_;
        #pragma unroll
        for (int li=0;li<4;++li) {
            int xq = ty*4 + li;
            float4 r;
            r.x = acc[li][0] + bias4.x;
            r.y = acc[li][1] + bias4.y;
            r.z = acc[li][2] + bias4.z;
            r.w = acc[li][3] + bias4.w;
            outp[plane + (size_t)(yq+PAD_)*PW_ + (xq+PAD_)] = r;
        }
    }
}

// ---------------- Kernel 2: 7x7 local attention, coalesced planar-c4 ------
// One wave per (b, h, row-pair y0..y0+1); lane = x. Output in-place over Q.
__global__ __launch_bounds__(64) void local_attn(
    float* __restrict__ qt, const float4* __restrict__ kt, const float4* __restrict__ vt)
{
    const int x  = threadIdx.x;
    const int y0 = blockIdx.x * 2;
    const int h  = blockIdx.y;
    const int b  = blockIdx.z;

    float* qp0 = qt + ((size_t)(b*L_ + y0*W_ + x)*C_ + h*DH_);
    float* qp1 = qp0 + (size_t)W_*C_;

    const float4* kb = kt + (size_t)(b*HEADS_ + h)*CG_*PPIX_;
    const float4* vb = vt + (size_t)(b*HEADS_ + h)*CG_*PPIX_;

    // ---- QK: accumulate logits for both pixels over 8 channel-groups ----
    float lg0[K2_] = {};
    float lg1[K2_] = {};
    #pragma unroll
    for (int cg=0; cg<CG_; ++cg) {
        const float4 qa = reinterpret_cast<const float4*>(qp0)[cg];
        const float4 qb = reinterpret_cast<const float4*>(qp1)[cg];
        const float4* plane = kb + (size_t)cg*PPIX_;
        #pragma unroll
        for (int r=0; r<8; ++r) {               // padded rows y0 .. y0+7
            const float4* row = plane + (size_t)(y0 + r)*PW_ + x;
            #pragma unroll
            for (int kx=0; kx<K_; ++kx) {
                float4 kv = row[kx];
                if (r < 7) {
                    float& L = lg0[r*K_+kx];
                    L = fmaf(qa.x,kv.x, fmaf(qa.y,kv.y, fmaf(qa.z,kv.z, fmaf(qa.w,kv.w, L))));
                }
                if (r > 0) {
                    float& L = lg1[(r-1)*K_+kx];
                    L = fmaf(qb.x,kv.x, fmaf(qb.y,kv.y, fmaf(qb.z,kv.z, fmaf(qb.w,kv.w, L))));
                }
            }
        }
    }

    // ---- softmax over 49 taps each (raw max, then scaled exp) ----
    const float scale = 0.0625f; // 1/sqrt(256)
    float m0 = lg0[0], m1 = lg1[0];
    #pragma unroll
    for (int s=1;s<K2_;++s) { m0 = fmaxf(m0, lg0[s]); m1 = fmaxf(m1, lg1[s]); }
    float s0 = 0.f, s1 = 0.f;
    #pragma unroll
    for (int s=0;s<K2_;++s) {
        lg0[s] = __expf((lg0[s]-m0)*scale); s0 += lg0[s];
        lg1[s] = __expf((lg1[s]-m1)*scale); s1 += lg1[s];
    }
    const float inv0 = 1.0f/s0, inv1 = 1.0f/s1;

    // ---- PV: per channel-group accumulate and store ----
    #pragma unroll
    for (int cg=0; cg<CG_; ++cg) {
        float4 a0 = make_float4(0.f,0.f,0.f,0.f);
        float4 a1 = make_float4(0.f,0.f,0.f,0.f);
        const float4* plane = vb + (size_t)cg*PPIX_;
        #pragma unroll
        for (int r=0; r<8; ++r) {
            const float4* row = plane + (size_t)(y0 + r)*PW_ + x;
            #pragma unroll
            for (int kx=0; kx<K_; ++kx) {
                float4 vv = row[kx];
                if (r < 7) {
                    float p = lg0[r*K_+kx];
                    a0.x = fmaf(p, vv.x, a0.x); a0.y = fmaf(p, vv.y, a0.y);
                    a0.z = fmaf(p, vv.z, a0.z); a0.w = fmaf(p, vv.w, a0.w);
                }
                if (r > 0) {
                    float p = lg1[(r-1)*K_+kx];
                    a1.x = fmaf(p, vv.x, a1.x); a1.y = fmaf(p, vv.y, a1.y);
                    a1.z = fmaf(p, vv.z, a1.z); a1.w = fmaf(p, vv.w, a1.w);
                }
            }
        }
        a0.x *= inv0; a0.y *= inv0; a0.z *= inv0; a0.w *= inv0;
        a1.x *= inv1; a1.y *= inv1; a1.z *= inv1; a1.w *= inv1;
        reinterpret_cast<float4*>(qp0)[cg] = a0;
        reinterpret_cast<float4*>(qp1)[cg] = a1;
    }
}

// ---------------- Kernel 3: output projection, NHWC -> NCHW ----------------
__global__ __launch_bounds__(256) void out_proj(
    const float* __restrict__ at, const float* __restrict__ wo, const float* __restrict__ bo,
    float* __restrict__ out)
{
    const int b = blockIdx.z;
    const int l0 = blockIdx.x*64;
    const int o0 = blockIdx.y*64;
    const int tx = threadIdx.x, ty = threadIdx.y;
    const int tid = ty*16+tx;

    __shared__ float As[16][68]; // [c][l]
    __shared__ float Bs[16][68]; // [c][o]

    float acc[4][4] = {}; // [oi][li]

    for (int c0=0;c0<C_;c0+=16) {
        #pragma unroll
        for (int i=0;i<4;++i) {
            int idx = tid + i*256;
            int l = idx >> 4, c = idx & 15;
            As[c][l] = at[(size_t)(b*L_ + l0 + l)*C_ + c0 + c];
        }
        #pragma unroll
        for (int i=0;i<4;++i) {
            int idx = tid + i*256;
            int o = idx >> 4, c = idx & 15;
            Bs[c][o] = wo[(size_t)(o0 + o)*C_ + c0 + c];
        }
        __syncthreads();
        #pragma unroll
        for (int cc=0;cc<16;++cc) {
            float a[4], bb[4];
            #pragma unroll
            for (int i=0;i<4;++i) a[i]  = As[cc][tx*4+i];
            #pragma unroll
            for (int i=0;i<4;++i) bb[i] = Bs[cc][ty*4+i];
            #pragma unroll
            for (int oi=0;oi<4;++oi)
                #pragma unroll
                for (int li=0;li<4;++li)
                    acc[oi][li] += bb[oi]*a[li];
        }
        __syncthreads();
    }
    #pragma unroll
    for (int oi=0;oi<4;++oi) {
        int o = o0 + ty*4 + oi;
        float bias = bo[o];
        float4 r;
        r.x = acc[oi][0] + bias;
        r.y = acc[oi][1] + bias;
        r.z = acc[oi][2] + bias;
        r.w = acc[oi][3] + bias;
        *reinterpret_cast<float4*>(&out[((size_t)b*C_ + o)*L_ + l0 + tx*4]) = r;
    }
}

extern "C" void kernel_launch(void* const* d_in, const int* in_sizes, int n_in,
                              void* d_out, int out_size, void* d_ws, size_t ws_size,
                              hipStream_t stream) {
    const float* queries = (const float*)d_in[0];
    const float* keys    = (const float*)d_in[1];
    const float* values  = (const float*)d_in[2];
    const float* wq = (const float*)d_in[3];
    const float* bq = (const float*)d_in[4];
    const float* wk = (const float*)d_in[5];
    const float* bk = (const float*)d_in[6];
    const float* wv = (const float*)d_in[7];
    const float* bv = (const float*)d_in[8];
    const float* wo = (const float*)d_in[9];
    const float* bo = (const float*)d_in[10];
    float* out = (float*)d_out;

    const size_t q_elems = (size_t)B_ * L_ * C_;   // 2,097,152 floats
    float*  qt = (float*)d_ws;                      // Q, then attn output in-place
    float4* kt = (float4*)(qt + q_elems);           // padded planar-c4 K
    float4* vt = kt + PADT4_;                       // padded planar-c4 V

    halo_zero<<<dim3((unsigned)((PADT4_ + 255)/256)), 256, 0, stream>>>(kt, vt);

    dim3 blk(16,16);
    qkv_proj<<<dim3(L_/64, C_/64, B_*3), blk, 0, stream>>>(
        queries, keys, values, wq, bq, wk, bk, wv, bv, qt, kt, vt);
    local_attn<<<dim3(H_/2, HEADS_, B_), 64, 0, stream>>>(qt, kt, vt);
    out_proj<<<dim3(L_/64, C_/64, B_), blk, 0, stream>>>(qt, wo, bo, out);
}

// Round 4
// 96.257 us; speedup vs baseline: 1.9405x; 1.3376x over previous
//
#include <hip/hip_runtime.h>
#include <hip/hip_bf16.h>
#include <math.h>

#define B_ 2
#define C_ 256
#define H_ 64
#define W_ 64
#define L_ 4096
#define HEADS_ 8
#define DH_ 32
#define CG_ 8
#define K_ 7
#define PAD_ 3
#define K2_ 49
#define PW_ 70
#define PPIX_ 4900
#define PADT4_ ((size_t)B_*HEADS_*CG_*PPIX_)   // 627200 float4 per padded tensor
#define WS_STR 72                               // LDS row stride in bf16 (144B, 16B-aligned)

typedef short bf16x8 __attribute__((ext_vector_type(8)));
typedef float f32x4  __attribute__((ext_vector_type(4)));

__device__ inline unsigned short f2bf(float f) {
    union { float f; unsigned u; } uf; uf.f = f;
    unsigned r = uf.u + 0x7fffu + ((uf.u >> 16) & 1u);   // RNE
    return (unsigned short)(r >> 16);
}

// ---------------- Kernel A: pack 4 weight matrices to bf16 (u32 pairs) ------
// wb layout: [which 0..3][o 0..255][c-pair 0..127] u32 (lo short = even c)
__global__ __launch_bounds__(256) void wconv(
    const float* __restrict__ wq, const float* __restrict__ wk,
    const float* __restrict__ wv, const float* __restrict__ wo,
    unsigned* __restrict__ wb)
{
    int idx = blockIdx.x*256 + threadIdx.x;   // 0..131071
    const float* src = (idx < 32768) ? wq : (idx < 65536) ? wk : (idx < 98304) ? wv : wo;
    int off = (idx & 32767) * 2;
    float a = src[off], b = src[off+1];
    wb[idx] = (unsigned)f2bf(a) | ((unsigned)f2bf(b) << 16);
}

// ---------------- Kernel B: zero the padded halo of K/V ----------------
__global__ __launch_bounds__(256) void halo_zero(float4* __restrict__ kt, float4* __restrict__ vt)
{
    int idx = blockIdx.x*256 + threadIdx.x;
    if (idx >= (int)PADT4_) return;
    int cell = idx % PPIX_;
    int px = cell % PW_, py = cell / PW_;
    if (px < PAD_ || px >= PW_-PAD_ || py < PAD_ || py >= PW_-PAD_) {
        float4 z = make_float4(0.f,0.f,0.f,0.f);
        kt[idx] = z;
        vt[idx] = z;
    }
}

// ---------------- Kernel C: QKV projection via bf16 MFMA -------------------
// D[o][l] = sum_c W[o][c] * X[c][l].  Block: all 256 o x 64 l (one image row).
// Outputs: Q -> planar-c4 [b][h][cg][l]; K/V -> padded planar [b][h][cg][py][px].
__global__ __launch_bounds__(256) void qkv_mfma(
    const float* __restrict__ q_in, const float* __restrict__ k_in, const float* __restrict__ v_in,
    const unsigned* __restrict__ wb,
    const float* __restrict__ bq, const float* __restrict__ bk, const float* __restrict__ bv,
    float4* __restrict__ qt4, float4* __restrict__ kt4, float4* __restrict__ vt4)
{
    const int z = blockIdx.z;
    const int which = z >> 1;      // 0=q,1=k,2=v
    const int b = z & 1;
    const float* X = (which==0) ? q_in : (which==1 ? k_in : v_in);
    const unsigned* wbp = wb + which*32768;
    const float* bias = (which==0) ? bq : (which==1 ? bk : bv);

    const int l0 = blockIdx.x * 64;
    const int tid = threadIdx.x;
    const int lane = tid & 63, wave = tid >> 6;
    const int orow = lane & 15, kgrp = lane >> 4;

    __shared__ short Ws[256*WS_STR];   // weights [o][c-chunk]
    __shared__ short Xs[64*WS_STR];    // input^T [l][c-chunk]

    f32x4 acc[4][4] = {};

    const int cq  = tid >> 6;   // 0..3
    const int lst = tid & 63;

    for (int ch = 0; ch < 4; ++ch) {
        const int c0 = ch*64;
        // stage Ws: 256 o x 64 c from pre-packed bf16 (uint2 = 4 c)
        #pragma unroll
        for (int i = 0; i < 16; ++i) {
            int o  = i*16 + (tid>>4);
            int c4 = tid & 15;
            uint2 v = *reinterpret_cast<const uint2*>(wbp + o*128 + (c0>>1) + c4*2);
            *reinterpret_cast<uint2*>(&Ws[o*WS_STR + c4*4]) = v;
        }
        // stage Xs: 64 l x 64 c, f32 -> bf16 with transpose (coalesced reads)
        #pragma unroll
        for (int i = 0; i < 8; ++i) {
            int cc = cq*2 + i*8;
            float a  = X[(size_t)(b*C_ + c0 + cc    )*L_ + l0 + lst];
            float b2 = X[(size_t)(b*C_ + c0 + cc + 1)*L_ + l0 + lst];
            unsigned pk = (unsigned)f2bf(a) | ((unsigned)f2bf(b2) << 16);
            *reinterpret_cast<unsigned*>(&Xs[lst*WS_STR + cc]) = pk;
        }
        __syncthreads();
        #pragma unroll
        for (int kk = 0; kk < 2; ++kk) {
            bf16x8 af[4], bfr[4];
            #pragma unroll
            for (int fo = 0; fo < 4; ++fo)
                af[fo] = *reinterpret_cast<const bf16x8*>(&Ws[(wave*64 + fo*16 + orow)*WS_STR + kk*32 + kgrp*8]);
            #pragma unroll
            for (int fn = 0; fn < 4; ++fn)
                bfr[fn] = *reinterpret_cast<const bf16x8*>(&Xs[(fn*16 + orow)*WS_STR + kk*32 + kgrp*8]);
            #pragma unroll
            for (int fo = 0; fo < 4; ++fo)
                #pragma unroll
                for (int fn = 0; fn < 4; ++fn)
                    acc[fo][fn] = __builtin_amdgcn_mfma_f32_16x16x32_bf16(af[fo], bfr[fn], acc[fo][fn], 0, 0, 0);
        }
        __syncthreads();
    }

    // epilogue: lane holds rows o_base..o_base+3 (consecutive c within head) at col l
    const int y = blockIdx.x;   // l-tile == one image row
    #pragma unroll
    for (int fo = 0; fo < 4; ++fo) {
        const int o_base = wave*64 + fo*16 + kgrp*4;
        const float4 b4 = *reinterpret_cast<const float4*>(&bias[o_base]);
        const size_t p = (size_t)(b*64 + (o_base >> 2));   // plane index
        #pragma unroll
        for (int fn = 0; fn < 4; ++fn) {
            const int xl = fn*16 + orow;
            float4 r;
            r.x = acc[fo][fn][0] + b4.x;
            r.y = acc[fo][fn][1] + b4.y;
            r.z = acc[fo][fn][2] + b4.z;
            r.w = acc[fo][fn][3] + b4.w;
            if (which == 0) {
                qt4[p*L_ + l0 + xl] = r;
            } else {
                float4* dst = (which==1) ? kt4 : vt4;
                dst[p*PPIX_ + (size_t)(y+PAD_)*PW_ + (xl+PAD_)] = r;
            }
        }
    }
}

// ---------------- Kernel D: 7x7 local attention (planar-c4, f32) -----------
__global__ __launch_bounds__(64) void local_attn(
    float4* __restrict__ qt4, const float4* __restrict__ kt4, const float4* __restrict__ vt4)
{
    const int x  = threadIdx.x;
    const int y0 = blockIdx.x * 2;
    const int h  = blockIdx.y;
    const int b  = blockIdx.z;

    float4* qpl = qt4 + (size_t)(b*HEADS_ + h)*CG_*L_;
    const float4* kb = kt4 + (size_t)(b*HEADS_ + h)*CG_*PPIX_;
    const float4* vb = vt4 + (size_t)(b*HEADS_ + h)*CG_*PPIX_;

    float lg0[K2_] = {};
    float lg1[K2_] = {};
    #pragma unroll
    for (int cg=0; cg<CG_; ++cg) {
        const float4 qa = qpl[(size_t)cg*L_ + y0*W_ + x];
        const float4 qb = qpl[(size_t)cg*L_ + (y0+1)*W_ + x];
        const float4* plane = kb + (size_t)cg*PPIX_;
        #pragma unroll
        for (int r=0; r<8; ++r) {
            const float4* row = plane + (size_t)(y0 + r)*PW_ + x;
            #pragma unroll
            for (int kx=0; kx<K_; ++kx) {
                float4 kv = row[kx];
                if (r < 7) {
                    float& Lg = lg0[r*K_+kx];
                    Lg = fmaf(qa.x,kv.x, fmaf(qa.y,kv.y, fmaf(qa.z,kv.z, fmaf(qa.w,kv.w, Lg))));
                }
                if (r > 0) {
                    float& Lg = lg1[(r-1)*K_+kx];
                    Lg = fmaf(qb.x,kv.x, fmaf(qb.y,kv.y, fmaf(qb.z,kv.z, fmaf(qb.w,kv.w, Lg))));
                }
            }
        }
    }

    const float scale = 0.0625f; // 1/sqrt(256)
    float m0 = lg0[0], m1 = lg1[0];
    #pragma unroll
    for (int s=1;s<K2_;++s) { m0 = fmaxf(m0, lg0[s]); m1 = fmaxf(m1, lg1[s]); }
    float s0 = 0.f, s1 = 0.f;
    #pragma unroll
    for (int s=0;s<K2_;++s) {
        lg0[s] = __expf((lg0[s]-m0)*scale); s0 += lg0[s];
        lg1[s] = __expf((lg1[s]-m1)*scale); s1 += lg1[s];
    }
    const float inv0 = 1.0f/s0, inv1 = 1.0f/s1;

    #pragma unroll
    for (int cg=0; cg<CG_; ++cg) {
        float4 a0 = make_float4(0.f,0.f,0.f,0.f);
        float4 a1 = make_float4(0.f,0.f,0.f,0.f);
        const float4* plane = vb + (size_t)cg*PPIX_;
        #pragma unroll
        for (int r=0; r<8; ++r) {
            const float4* row = plane + (size_t)(y0 + r)*PW_ + x;
            #pragma unroll
            for (int kx=0; kx<K_; ++kx) {
                float4 vv = row[kx];
                if (r < 7) {
                    float pp = lg0[r*K_+kx];
                    a0.x = fmaf(pp, vv.x, a0.x); a0.y = fmaf(pp, vv.y, a0.y);
                    a0.z = fmaf(pp, vv.z, a0.z); a0.w = fmaf(pp, vv.w, a0.w);
                }
                if (r > 0) {
                    float pp = lg1[(r-1)*K_+kx];
                    a1.x = fmaf(pp, vv.x, a1.x); a1.y = fmaf(pp, vv.y, a1.y);
                    a1.z = fmaf(pp, vv.z, a1.z); a1.w = fmaf(pp, vv.w, a1.w);
                }
            }
        }
        a0.x *= inv0; a0.y *= inv0; a0.z *= inv0; a0.w *= inv0;
        a1.x *= inv1; a1.y *= inv1; a1.z *= inv1; a1.w *= inv1;
        qpl[(size_t)cg*L_ + y0*W_ + x] = a0;
        qpl[(size_t)cg*L_ + (y0+1)*W_ + x] = a1;
    }
}

// ---------------- Kernel E: output projection via bf16 MFMA ----------------
// out[o][l] = sum_c Wo[o][c] * attn[c][l];  attn planar-c4 f32 in qt4.
__global__ __launch_bounds__(256) void out_mfma(
    const float4* __restrict__ qt4, const unsigned* __restrict__ wb,
    const float* __restrict__ bo, float* __restrict__ out)
{
    const int b  = blockIdx.z;
    const int l0 = blockIdx.x * 64;
    const int o_t0 = blockIdx.y * 128;
    const unsigned* wbp = wb + 3*32768;
    const int tid = threadIdx.x;
    const int lane = tid & 63, wave = tid >> 6;
    const int orow = lane & 15, kgrp = lane >> 4;

    __shared__ short Ws[128*WS_STR];
    __shared__ short Xs[64*WS_STR];

    f32x4 acc[2][4] = {};
    const int cq  = tid >> 6;
    const int lst = tid & 63;

    for (int ch = 0; ch < 4; ++ch) {
        const int c0 = ch*64;
        #pragma unroll
        for (int i = 0; i < 8; ++i) {
            int o  = i*16 + (tid>>4);
            int c4 = tid & 15;
            uint2 v = *reinterpret_cast<const uint2*>(wbp + (size_t)(o_t0 + o)*128 + (c0>>1) + c4*2);
            *reinterpret_cast<uint2*>(&Ws[o*WS_STR + c4*4]) = v;
        }
        #pragma unroll
        for (int i = 0; i < 4; ++i) {
            int c4i = i*4 + cq;      // chunk-local float4 group 0..15
            float4 vv = qt4[(size_t)(b*64 + (c0>>2) + c4i)*L_ + l0 + lst];
            unsigned p0 = (unsigned)f2bf(vv.x) | ((unsigned)f2bf(vv.y) << 16);
            unsigned p1 = (unsigned)f2bf(vv.z) | ((unsigned)f2bf(vv.w) << 16);
            *reinterpret_cast<unsigned*>(&Xs[lst*WS_STR + c4i*4    ]) = p0;
            *reinterpret_cast<unsigned*>(&Xs[lst*WS_STR + c4i*4 + 2]) = p1;
        }
        __syncthreads();
        #pragma unroll
        for (int kk = 0; kk < 2; ++kk) {
            bf16x8 af[2], bfr[4];
            #pragma unroll
            for (int fo = 0; fo < 2; ++fo)
                af[fo] = *reinterpret_cast<const bf16x8*>(&Ws[(wave*32 + fo*16 + orow)*WS_STR + kk*32 + kgrp*8]);
            #pragma unroll
            for (int fn = 0; fn < 4; ++fn)
                bfr[fn] = *reinterpret_cast<const bf16x8*>(&Xs[(fn*16 + orow)*WS_STR + kk*32 + kgrp*8]);
            #pragma unroll
            for (int fo = 0; fo < 2; ++fo)
                #pragma unroll
                for (int fn = 0; fn < 4; ++fn)
                    acc[fo][fn] = __builtin_amdgcn_mfma_f32_16x16x32_bf16(af[fo], bfr[fn], acc[fo][fn], 0, 0, 0);
        }
        __syncthreads();
    }

    #pragma unroll
    for (int fo = 0; fo < 2; ++fo) {
        const int o_base = o_t0 + wave*32 + fo*16 + kgrp*4;
        #pragma unroll
        for (int fn = 0; fn < 4; ++fn) {
            const int xl = fn*16 + orow;
            #pragma unroll
            for (int r = 0; r < 4; ++r)
                out[(size_t)(b*C_ + o_base + r)*L_ + l0 + xl] = acc[fo][fn][r] + bo[o_base + r];
        }
    }
}

extern "C" void kernel_launch(void* const* d_in, const int* in_sizes, int n_in,
                              void* d_out, int out_size, void* d_ws, size_t ws_size,
                              hipStream_t stream) {
    const float* queries = (const float*)d_in[0];
    const float* keys    = (const float*)d_in[1];
    const float* values  = (const float*)d_in[2];
    const float* wq = (const float*)d_in[3];
    const float* bq = (const float*)d_in[4];
    const float* wk = (const float*)d_in[5];
    const float* bk = (const float*)d_in[6];
    const float* wv = (const float*)d_in[7];
    const float* bv = (const float*)d_in[8];
    const float* wo = (const float*)d_in[9];
    const float* bo = (const float*)d_in[10];
    float* out = (float*)d_out;

    float4* qt4 = (float4*)d_ws;                           // 524288 f4 (Q, then attn out in-place)
    float4* kt4 = qt4 + (size_t)B_*HEADS_*CG_*L_;          // padded planar K
    float4* vt4 = kt4 + PADT4_;                            // padded planar V
    unsigned* wb = (unsigned*)(vt4 + PADT4_);              // 131072 u32 bf16 weights

    wconv<<<512, 256, 0, stream>>>(wq, wk, wv, wo, wb);
    halo_zero<<<dim3((unsigned)((PADT4_ + 255)/256)), 256, 0, stream>>>(kt4, vt4);
    qkv_mfma<<<dim3(64, 1, 6), 256, 0, stream>>>(queries, keys, values, wb, bq, bk, bv, qt4, kt4, vt4);
    local_attn<<<dim3(H_/2, HEADS_, B_), 64, 0, stream>>>(qt4, kt4, vt4);
    out_mfma<<<dim3(64, 2, 2), 256, 0, stream>>>(qt4, wb, bo, out);
}

// Round 5
// 70.956 us; speedup vs baseline: 2.6325x; 1.3566x over previous
//
#include <hip/hip_runtime.h>
#include <hip/hip_bf16.h>
#include <math.h>

#define B_ 2
#define C_ 256
#define H_ 64
#define W_ 64
#define L_ 4096
#define HEADS_ 8
#define DH_ 32
#define CG_ 8
#define K_ 7
#define PAD_ 3
#define K2_ 49
#define PW_ 70
#define PPIX_ 4900
#define PADT4_ ((size_t)B_*HEADS_*CG_*PPIX_)   // 627200 float4 per padded tensor
#define WS_STR 72                               // LDS row stride in bf16 (144B, 16B-aligned)

typedef short bf16x8 __attribute__((ext_vector_type(8)));
typedef float f32x4  __attribute__((ext_vector_type(4)));

__device__ inline unsigned short f2bf(float f) {
    union { float f; unsigned u; } uf; uf.f = f;
    unsigned r = uf.u + 0x7fffu + ((uf.u >> 16) & 1u);   // RNE
    return (unsigned short)(r >> 16);
}

// ---------------- Kernel A: pack 4 weight matrices to bf16 (u32 pairs) ------
__global__ __launch_bounds__(256) void wconv(
    const float* __restrict__ wq, const float* __restrict__ wk,
    const float* __restrict__ wv, const float* __restrict__ wo,
    unsigned* __restrict__ wb)
{
    int idx = blockIdx.x*256 + threadIdx.x;   // 0..131071
    const float* src = (idx < 32768) ? wq : (idx < 65536) ? wk : (idx < 98304) ? wv : wo;
    int off = (idx & 32767) * 2;
    float a = src[off], b = src[off+1];
    wb[idx] = (unsigned)f2bf(a) | ((unsigned)f2bf(b) << 16);
}

// ---------------- Kernel B: zero the padded halo of K/V ----------------
__global__ __launch_bounds__(256) void halo_zero(float4* __restrict__ kt, float4* __restrict__ vt)
{
    int idx = blockIdx.x*256 + threadIdx.x;
    if (idx >= (int)PADT4_) return;
    int cell = idx % PPIX_;
    int px = cell % PW_, py = cell / PW_;
    if (px < PAD_ || px >= PW_-PAD_ || py < PAD_ || py >= PW_-PAD_) {
        float4 z = make_float4(0.f,0.f,0.f,0.f);
        kt[idx] = z;
        vt[idx] = z;
    }
}

// ---------------- Kernel C: QKV projection via bf16 MFMA -------------------
__global__ __launch_bounds__(256) void qkv_mfma(
    const float* __restrict__ q_in, const float* __restrict__ k_in, const float* __restrict__ v_in,
    const unsigned* __restrict__ wb,
    const float* __restrict__ bq, const float* __restrict__ bk, const float* __restrict__ bv,
    float4* __restrict__ qt4, float4* __restrict__ kt4, float4* __restrict__ vt4)
{
    const int z = blockIdx.z;
    const int which = z >> 1;      // 0=q,1=k,2=v
    const int b = z & 1;
    const float* X = (which==0) ? q_in : (which==1 ? k_in : v_in);
    const unsigned* wbp = wb + which*32768;
    const float* bias = (which==0) ? bq : (which==1 ? bk : bv);

    const int l0 = blockIdx.x * 64;
    const int tid = threadIdx.x;
    const int lane = tid & 63, wave = tid >> 6;
    const int orow = lane & 15, kgrp = lane >> 4;

    __shared__ short Ws[256*WS_STR];   // weights [o][c-chunk]
    __shared__ short Xs[64*WS_STR];    // input^T [l][c-chunk]

    f32x4 acc[4][4] = {};

    const int cq  = tid >> 6;   // 0..3
    const int lst = tid & 63;

    for (int ch = 0; ch < 4; ++ch) {
        const int c0 = ch*64;
        #pragma unroll
        for (int i = 0; i < 16; ++i) {
            int o  = i*16 + (tid>>4);
            int c4 = tid & 15;
            uint2 v = *reinterpret_cast<const uint2*>(wbp + o*128 + (c0>>1) + c4*2);
            *reinterpret_cast<uint2*>(&Ws[o*WS_STR + c4*4]) = v;
        }
        #pragma unroll
        for (int i = 0; i < 8; ++i) {
            int cc = cq*2 + i*8;
            float a  = X[(size_t)(b*C_ + c0 + cc    )*L_ + l0 + lst];
            float b2 = X[(size_t)(b*C_ + c0 + cc + 1)*L_ + l0 + lst];
            unsigned pk = (unsigned)f2bf(a) | ((unsigned)f2bf(b2) << 16);
            *reinterpret_cast<unsigned*>(&Xs[lst*WS_STR + cc]) = pk;
        }
        __syncthreads();
        #pragma unroll
        for (int kk = 0; kk < 2; ++kk) {
            bf16x8 af[4], bfr[4];
            #pragma unroll
            for (int fo = 0; fo < 4; ++fo)
                af[fo] = *reinterpret_cast<const bf16x8*>(&Ws[(wave*64 + fo*16 + orow)*WS_STR + kk*32 + kgrp*8]);
            #pragma unroll
            for (int fn = 0; fn < 4; ++fn)
                bfr[fn] = *reinterpret_cast<const bf16x8*>(&Xs[(fn*16 + orow)*WS_STR + kk*32 + kgrp*8]);
            #pragma unroll
            for (int fo = 0; fo < 4; ++fo)
                #pragma unroll
                for (int fn = 0; fn < 4; ++fn)
                    acc[fo][fn] = __builtin_amdgcn_mfma_f32_16x16x32_bf16(af[fo], bfr[fn], acc[fo][fn], 0, 0, 0);
        }
        __syncthreads();
    }

    const int y = blockIdx.x;   // l-tile == one image row
    #pragma unroll
    for (int fo = 0; fo < 4; ++fo) {
        const int o_base = wave*64 + fo*16 + kgrp*4;
        const float4 b4 = *reinterpret_cast<const float4*>(&bias[o_base]);
        const size_t p = (size_t)(b*64 + (o_base >> 2));   // plane index
        #pragma unroll
        for (int fn = 0; fn < 4; ++fn) {
            const int xl = fn*16 + orow;
            float4 r;
            r.x = acc[fo][fn][0] + b4.x;
            r.y = acc[fo][fn][1] + b4.y;
            r.z = acc[fo][fn][2] + b4.z;
            r.w = acc[fo][fn][3] + b4.w;
            if (which == 0) {
                qt4[p*L_ + l0 + xl] = r;
            } else {
                float4* dst = (which==1) ? kt4 : vt4;
                dst[p*PPIX_ + (size_t)(y+PAD_)*PW_ + (xl+PAD_)] = r;
            }
        }
    }
}

// ---------------- Kernel D: 7x7 local attention, 4-wave cooperative --------
// Block = (plane = b*8+h, row-pair y0,y0+1). 4 waves:
//   QK split by window row (wave w -> padded rows y0+2w, y0+2w+1), full channel sum
//   logits exchanged via LDS; softmax duplicated per wave (registers)
//   PV split by channel-group (wave w -> cg 2w, 2w+1), no reduction needed.
__global__ __launch_bounds__(256) void local_attn(
    float4* __restrict__ qt4, const float4* __restrict__ kt4, const float4* __restrict__ vt4)
{
    const int tid = threadIdx.x;
    const int w = tid >> 6;
    const int x = tid & 63;
    const int bid = blockIdx.x;
    const int plane = bid & 15;          // b*HEADS_ + h  (XCD-friendly: plane = bid%16)
    const int y0 = (bid >> 4) * 2;

    const float4* kb = kt4 + (size_t)plane*CG_*PPIX_;
    const float4* vb = vt4 + (size_t)plane*CG_*PPIX_;
    float4* qpl = qt4 + (size_t)plane*CG_*L_;

    __shared__ float Ls0[K2_][64];
    __shared__ float Ls1[K2_][64];

    // Q for both pixels, all channel groups
    float4 qa[CG_], qb[CG_];
    #pragma unroll
    for (int cg=0; cg<CG_; ++cg) {
        qa[cg] = qpl[(size_t)cg*L_ + (y0  )*W_ + x];
        qb[cg] = qpl[(size_t)cg*L_ + (y0+1)*W_ + x];
    }

    // ---- QK: my two window rows (r = 2w, 2w+1 of 0..7) ----
    float lgA[2][K_];   // -> pixel0 (valid when r<7)
    float lgB[2][K_];   // -> pixel1 (valid when r>0)
    #pragma unroll
    for (int rr=0; rr<2; ++rr)
        #pragma unroll
        for (int kx=0; kx<K_; ++kx) { lgA[rr][kx]=0.f; lgB[rr][kx]=0.f; }

    #pragma unroll
    for (int cg=0; cg<CG_; ++cg) {
        #pragma unroll
        for (int rr=0; rr<2; ++rr) {
            const int r = w*2 + rr;
            const float4* row = kb + (size_t)cg*PPIX_ + (size_t)(y0 + r)*PW_ + x;
            #pragma unroll
            for (int kx=0; kx<K_; ++kx) {
                float4 kv = row[kx];
                float4 q0 = qa[cg], q1 = qb[cg];
                lgA[rr][kx] = fmaf(q0.x,kv.x, fmaf(q0.y,kv.y, fmaf(q0.z,kv.z, fmaf(q0.w,kv.w, lgA[rr][kx]))));
                lgB[rr][kx] = fmaf(q1.x,kv.x, fmaf(q1.y,kv.y, fmaf(q1.z,kv.z, fmaf(q1.w,kv.w, lgB[rr][kx]))));
            }
        }
    }
    #pragma unroll
    for (int rr=0; rr<2; ++rr) {
        const int r = w*2 + rr;
        if (r < 7) {
            #pragma unroll
            for (int kx=0; kx<K_; ++kx) Ls0[r*K_+kx][x] = lgA[rr][kx];
        }
        if (r > 0) {
            #pragma unroll
            for (int kx=0; kx<K_; ++kx) Ls1[(r-1)*K_+kx][x] = lgB[rr][kx];
        }
    }
    __syncthreads();

    // ---- softmax (each wave computes both pixels' P in registers) ----
    float p0[K2_], p1[K2_];
    #pragma unroll
    for (int t=0;t<K2_;++t) { p0[t] = Ls0[t][x]; p1[t] = Ls1[t][x]; }
    const float scale = 0.0625f; // 1/sqrt(256)
    float m0 = p0[0], m1 = p1[0];
    #pragma unroll
    for (int t=1;t<K2_;++t) { m0 = fmaxf(m0, p0[t]); m1 = fmaxf(m1, p1[t]); }
    float s0 = 0.f, s1 = 0.f;
    #pragma unroll
    for (int t=0;t<K2_;++t) {
        p0[t] = __expf((p0[t]-m0)*scale); s0 += p0[t];
        p1[t] = __expf((p1[t]-m1)*scale); s1 += p1[t];
    }
    const float inv0 = 1.0f/s0, inv1 = 1.0f/s1;

    // ---- PV: my two channel groups, all taps, both pixels ----
    #pragma unroll
    for (int cgi=0; cgi<2; ++cgi) {
        const int cg = w*2 + cgi;
        float4 a0 = make_float4(0.f,0.f,0.f,0.f);
        float4 a1 = make_float4(0.f,0.f,0.f,0.f);
        const float4* plv = vb + (size_t)cg*PPIX_;
        #pragma unroll
        for (int r=0; r<8; ++r) {
            const float4* row = plv + (size_t)(y0 + r)*PW_ + x;
            #pragma unroll
            for (int kx=0; kx<K_; ++kx) {
                float4 vv = row[kx];
                if (r < 7) {
                    float pp = p0[r*K_+kx];
                    a0.x = fmaf(pp, vv.x, a0.x); a0.y = fmaf(pp, vv.y, a0.y);
                    a0.z = fmaf(pp, vv.z, a0.z); a0.w = fmaf(pp, vv.w, a0.w);
                }
                if (r > 0) {
                    float pp = p1[(r-1)*K_+kx];
                    a1.x = fmaf(pp, vv.x, a1.x); a1.y = fmaf(pp, vv.y, a1.y);
                    a1.z = fmaf(pp, vv.z, a1.z); a1.w = fmaf(pp, vv.w, a1.w);
                }
            }
        }
        a0.x *= inv0; a0.y *= inv0; a0.z *= inv0; a0.w *= inv0;
        a1.x *= inv1; a1.y *= inv1; a1.z *= inv1; a1.w *= inv1;
        qpl[(size_t)cg*L_ + (y0  )*W_ + x] = a0;
        qpl[(size_t)cg*L_ + (y0+1)*W_ + x] = a1;
    }
}

// ---------------- Kernel E: output projection via bf16 MFMA ----------------
__global__ __launch_bounds__(256) void out_mfma(
    const float4* __restrict__ qt4, const unsigned* __restrict__ wb,
    const float* __restrict__ bo, float* __restrict__ out)
{
    const int b  = blockIdx.z;
    const int l0 = blockIdx.x * 64;
    const int o_t0 = blockIdx.y * 128;
    const unsigned* wbp = wb + 3*32768;
    const int tid = threadIdx.x;
    const int lane = tid & 63, wave = tid >> 6;
    const int orow = lane & 15, kgrp = lane >> 4;

    __shared__ short Ws[128*WS_STR];
    __shared__ short Xs[64*WS_STR];

    f32x4 acc[2][4] = {};
    const int cq  = tid >> 6;
    const int lst = tid & 63;

    for (int ch = 0; ch < 4; ++ch) {
        const int c0 = ch*64;
        #pragma unroll
        for (int i = 0; i < 8; ++i) {
            int o  = i*16 + (tid>>4);
            int c4 = tid & 15;
            uint2 v = *reinterpret_cast<const uint2*>(wbp + (size_t)(o_t0 + o)*128 + (c0>>1) + c4*2);
            *reinterpret_cast<uint2*>(&Ws[o*WS_STR + c4*4]) = v;
        }
        #pragma unroll
        for (int i = 0; i < 4; ++i) {
            int c4i = i*4 + cq;
            float4 vv = qt4[(size_t)(b*64 + (c0>>2) + c4i)*L_ + l0 + lst];
            unsigned pk0 = (unsigned)f2bf(vv.x) | ((unsigned)f2bf(vv.y) << 16);
            unsigned pk1 = (unsigned)f2bf(vv.z) | ((unsigned)f2bf(vv.w) << 16);
            *reinterpret_cast<unsigned*>(&Xs[lst*WS_STR + c4i*4    ]) = pk0;
            *reinterpret_cast<unsigned*>(&Xs[lst*WS_STR + c4i*4 + 2]) = pk1;
        }
        __syncthreads();
        #pragma unroll
        for (int kk = 0; kk < 2; ++kk) {
            bf16x8 af[2], bfr[4];
            #pragma unroll
            for (int fo = 0; fo < 2; ++fo)
                af[fo] = *reinterpret_cast<const bf16x8*>(&Ws[(wave*32 + fo*16 + orow)*WS_STR + kk*32 + kgrp*8]);
            #pragma unroll
            for (int fn = 0; fn < 4; ++fn)
                bfr[fn] = *reinterpret_cast<const bf16x8*>(&Xs[(fn*16 + orow)*WS_STR + kk*32 + kgrp*8]);
            #pragma unroll
            for (int fo = 0; fo < 2; ++fo)
                #pragma unroll
                for (int fn = 0; fn < 4; ++fn)
                    acc[fo][fn] = __builtin_amdgcn_mfma_f32_16x16x32_bf16(af[fo], bfr[fn], acc[fo][fn], 0, 0, 0);
        }
        __syncthreads();
    }

    #pragma unroll
    for (int fo = 0; fo < 2; ++fo) {
        const int o_base = o_t0 + wave*32 + fo*16 + kgrp*4;
        #pragma unroll
        for (int fn = 0; fn < 4; ++fn) {
            const int xl = fn*16 + orow;
            #pragma unroll
            for (int r = 0; r < 4; ++r)
                out[(size_t)(b*C_ + o_base + r)*L_ + l0 + xl] = acc[fo][fn][r] + bo[o_base + r];
        }
    }
}

extern "C" void kernel_launch(void* const* d_in, const int* in_sizes, int n_in,
                              void* d_out, int out_size, void* d_ws, size_t ws_size,
                              hipStream_t stream) {
    const float* queries = (const float*)d_in[0];
    const float* keys    = (const float*)d_in[1];
    const float* values  = (const float*)d_in[2];
    const float* wq = (const float*)d_in[3];
    const float* bq = (const float*)d_in[4];
    const float* wk = (const float*)d_in[5];
    const float* bk = (const float*)d_in[6];
    const float* wv = (const float*)d_in[7];
    const float* bv = (const float*)d_in[8];
    const float* wo = (const float*)d_in[9];
    const float* bo = (const float*)d_in[10];
    float* out = (float*)d_out;

    float4* qt4 = (float4*)d_ws;                           // Q planar-c4, attn out in-place
    float4* kt4 = qt4 + (size_t)B_*HEADS_*CG_*L_;          // padded planar K
    float4* vt4 = kt4 + PADT4_;                            // padded planar V
    unsigned* wb = (unsigned*)(vt4 + PADT4_);              // bf16 packed weights

    wconv<<<512, 256, 0, stream>>>(wq, wk, wv, wo, wb);
    halo_zero<<<dim3((unsigned)((PADT4_ + 255)/256)), 256, 0, stream>>>(kt4, vt4);
    qkv_mfma<<<dim3(64, 1, 6), 256, 0, stream>>>(queries, keys, values, wb, bq, bk, bv, qt4, kt4, vt4);
    local_attn<<<512, 256, 0, stream>>>(qt4, kt4, vt4);
    out_mfma<<<dim3(64, 2, 2), 256, 0, stream>>>(qt4, wb, bo, out);
}